// Round 3
// baseline (165.794 us; speedup 1.0000x reference)
//
#include <hip/hip_runtime.h>

// SPN forward, round 3: single wave per plane, direct-to-register streaming.
// [B*C=256 planes] x [H=256] x [W=256] fp32. Lane l owns rows 4l..4l+3;
// h-state in registers; vertical exchange = 2 shuffles/col; NO barriers,
// NO input LDS. Inputs load straight into registers in consumer layout
// (lane-private rows), double-buffered across 8-col stages with
// compiler-managed vmcnt. Gate normalization hoisted out of the serial
// chain. Output transposed through a small LDS tile -> coalesced stores.

#define HD 256
#define WD 256
#define SW 8                 // stage width (columns)
#define NS (WD / SW)         // 32 stages
#define TS 260               // out tile col stride (floats): 2-way banks max

#define F4E(v, e) ((e) == 0 ? (v).x : (e) == 1 ? (v).y : (e) == 2 ? (v).z : (v).w)

struct Stage { float4 v[4][8]; };   // [array][r*2 + half]; float4 = 4 cols

__global__ __launch_bounds__(64, 1) void spn_fwd(
    const float* __restrict__ x, const float* __restrict__ G1,
    const float* __restrict__ G2, const float* __restrict__ G3,
    float* __restrict__ out)
{
  // only ~8.3 KB used (out-transpose tile); padded so exactly 1 block/CU
  __shared__ __align__(16) char ldsbuf[83200];
  float* tileF = (float*)ldsbuf;

  const int l = threadIdx.x;
  const size_t pbase = (size_t)blockIdx.x * (HD * WD);
  const float* gp[4] = {x + pbase, G1 + pbase, G2 + pbase, G3 + pbase};
  float* op = out + pbase;

  const float mU = (l > 0) ? 1.f : 0.f;     // row 0 has no up neighbor
  const float mD = (l < 63) ? 1.f : 0.f;    // row 255 has no down neighbor

  float h[4] = {0.f, 0.f, 0.f, 0.f};

  // ---- load one half (4 cols) of a stage into consumer-layout registers
  auto issueHalf = [&](Stage& N, int j0n, int half) {
#pragma unroll
    for (int A = 0; A < 4; ++A)
#pragma unroll
      for (int r = 0; r < 4; ++r)
        N.v[A][r * 2 + half] =
            *(const float4*)(gp[A] + (size_t)(4 * l + r) * WD + j0n + 4 * half);
  };

  // ---- bulk gate-normalize a stage in place; x-slot becomes (1-sum(g))*x
  auto normalize = [&](Stage& C, float cm) {
#pragma unroll
    for (int k = 0; k < 8; ++k) {
      const int r = k >> 1;
      float4 X = C.v[0][k], Av = C.v[1][k], Bv = C.v[2][k], Cv = C.v[3][k];
      float dx[4], da[4], db[4], dc[4];
#pragma unroll
      for (int e = 0; e < 4; ++e) {
        float a = F4E(Av, e), b = F4E(Bv, e), c = F4E(Cv, e);
        float s = fabsf(a) + fabsf(b) + fabsf(c);
        float inv = (s >= 1.f) ? __builtin_amdgcn_rcpf(s) : 1.f;
        a *= inv; b *= inv; c *= inv;
        if ((k & 1) == 0 && e == 0) { a *= cm; b *= cm; c *= cm; }  // stage col 0
        if (r == 0) a *= mU;
        if (r == 3) c *= mD;
        dx[e] = (1.f - a - b - c) * F4E(X, e);
        da[e] = a; db[e] = b; dc[e] = c;
      }
      C.v[0][k] = make_float4(dx[0], dx[1], dx[2], dx[3]);
      C.v[1][k] = make_float4(da[0], da[1], da[2], da[3]);
      C.v[2][k] = make_float4(db[0], db[1], db[2], db[3]);
      C.v[3][k] = make_float4(dc[0], dc[1], dc[2], dc[3]);
    }
  };

  // ---- serial scan of 4 columns (one half); critical path = shfl + 3 FMA
  auto scanHalf = [&](Stage& C, int half) {
#pragma unroll
    for (int e = 0; e < 4; ++e) {
      const float shU = __shfl_up(h[3], 1);    // h[4l-1] from lane l-1
      const float shD = __shfl_down(h[0], 1);  // h[4l+4] from lane l+1
      float hn[4];
#pragma unroll
      for (int r = 0; r < 4; ++r) {
        const int k = r * 2 + half;
        float d  = F4E(C.v[0][k], e);
        float ga = F4E(C.v[1][k], e);
        float gb = F4E(C.v[2][k], e);
        float gc = F4E(C.v[3][k], e);
        float up = (r == 0) ? shU : h[r - 1];
        float dn = (r == 3) ? shD : h[r + 1];
        hn[r] = fmaf(ga, up, fmaf(gb, h[r], fmaf(gc, dn, d)));
      }
#pragma unroll
      for (int r = 0; r < 4; ++r) h[r] = hn[r];
      *(float4*)(tileF + (half * 4 + e) * TS + 4 * l) =
          make_float4(hn[0], hn[1], hn[2], hn[3]);
    }
  };

  // ---- coalesced stores from the transposed tile (2-way banks, verified)
  auto storeOut = [&](int j0) {
    const int srow = l >> 1, scol = (l & 1) * 4;
#pragma unroll
    for (int s = 0; s < 8; ++s) {
      const int row = s * 32 + srow;
      float4 o;
      o.x = tileF[(scol + 0) * TS + row];
      o.y = tileF[(scol + 1) * TS + row];
      o.z = tileF[(scol + 2) * TS + row];
      o.w = tileF[(scol + 3) * TS + row];
      *(float4*)(op + (size_t)row * WD + j0 + scol) = o;
    }
  };

  Stage A, B;
  issueHalf(A, 0, 0);
  issueHalf(A, 0, 1);

#pragma unroll 1
  for (int t = 0; t < NS; t += 2) {
    {   // consume A (stage t), prefetch stage t+1 into B (always valid: t<=30)
      const int j0 = t * SW;
      issueHalf(B, j0 + SW, 0);
      normalize(A, (t == 0) ? 0.f : 1.f);
      scanHalf(A, 0);
      issueHalf(B, j0 + SW, 1);
      scanHalf(A, 1);
      storeOut(j0);
    }
    {   // consume B (stage t+1), prefetch stage t+2 into A
      const int j0 = (t + 1) * SW;
      const bool pf = (t + 2 < NS);
      if (pf) issueHalf(A, j0 + SW, 0);
      normalize(B, 1.f);
      scanHalf(B, 0);
      if (pf) issueHalf(A, j0 + SW, 1);
      scanHalf(B, 1);
      storeOut(j0);
    }
  }
}

extern "C" void kernel_launch(void* const* d_in, const int* in_sizes, int n_in,
                              void* d_out, int out_size, void* d_ws, size_t ws_size,
                              hipStream_t stream) {
  const float* x  = (const float*)d_in[0];
  const float* g1 = (const float*)d_in[1];
  const float* g2 = (const float*)d_in[2];
  const float* g3 = (const float*)d_in[3];
  float* outp = (float*)d_out;
  const int planes = out_size / (HD * WD);   // B*C = 256
  spn_fwd<<<planes, 64, 0, stream>>>(x, g1, g2, g3, outp);
}

// Round 5
// 100.469 us; speedup vs baseline: 1.6502x; 1.6502x over previous
//
#include <hip/hip_runtime.h>

// SPN forward, round 5: uniform-loop producer/consumer specialization.
// One block per (b,c) plane: 320 threads = 4 producer waves + 1 consumer.
// ALL waves run the SAME loop; the single FENCE_BAR per iteration sits at
// one program point (role branch inside) -> barrier matching by construction.
// Producers: coalesced full-line loads (16 rows x 16 cols per inst), bulk
// gate-normalize + masks in regs, transpose-write to column-major LDS ring
// (3-deep, stage t+2 written while stage t is read). lgkmcnt-only barriers:
// producer global loads stay in flight across barriers.
// Consumer: serial scan, lane l = rows 4l..4l+3 in regs, 2 shuffles/col,
// dumps columns to an LDS tile, stores full 64B lines per 16-col pair.

#define HD 256
#define WD 256
#define NS 32                   // 8-col stages
#define STG 260                 // padded column stride (floats): 2-way banks
#define ARR_F (8 * STG)         // one array, one stage
#define STAGE_F (4 * ARR_F)     // one stage: d, g1, g2, g3
#define TILE_OFF (3 * STAGE_F)  // out tile after the 3-deep ring

#define F4E(v, e) ((e) == 0 ? (v).x : (e) == 1 ? (v).y : (e) == 2 ? (v).z : (v).w)

#define FENCE_BAR()                                      \
  do {                                                   \
    asm volatile("s_waitcnt lgkmcnt(0)" ::: "memory");   \
    __builtin_amdgcn_s_barrier();                        \
    asm volatile("" ::: "memory");                       \
  } while (0)

__global__ __launch_bounds__(320, 1) void spn_fwd(
    const float* __restrict__ x, const float* __restrict__ G1,
    const float* __restrict__ G2, const float* __restrict__ G3,
    float* __restrict__ out)
{
  __shared__ float lds_f[3 * STAGE_F + 16 * STG];   // 116,480 B -> 1 block/CU

  const int tid = threadIdx.x;
  const int wid = tid >> 6;          // 0..3 producers, 4 consumer
  const int l   = tid & 63;
  const size_t pbase = (size_t)blockIdx.x * (HD * WD);
  const float* gp[4] = {x + pbase, G1 + pbase, G2 + pbase, G3 + pbase};
  float* op = out + pbase;

  if (wid < 4) {
    // ===================== PRODUCER (rows 64*wid .. +63) =====================
    const int rq = l >> 2;           // row-in-16-group
    const int cq = l & 3;            // col quad (4 cols) within 16-col block
    const int myhalf = cq >> 1;      // 0: block cols 0-7, 1: cols 8-15
    float4 R[4][4];                  // [array][row-group i]; one 16-col block

    // coalesced: lanes 0-3 cover 64B of one row; inst covers 16 rows x 16 cols
    auto issueBlk = [&](int k) {
#pragma unroll
      for (int A = 0; A < 4; ++A)
#pragma unroll
        for (int i = 0; i < 4; ++i)
          R[A][i] = *(const float4*)(gp[A] +
              (size_t)(64 * wid + 16 * i + rq) * WD + 16 * k + 4 * cq);
    };

    // bulk normalize + masks; x-slot := (1-ga-gb-gc)*x
    auto normBlk = [&](int k) {
#pragma unroll
      for (int i = 0; i < 4; ++i) {
        const int row = 64 * wid + 16 * i + rq;
        const float uOk = (row > 0) ? 1.f : 0.f;
        const float dOk = (row < HD - 1) ? 1.f : 0.f;
        float nx[4], na[4], nb[4], nc[4];
#pragma unroll
        for (int e = 0; e < 4; ++e) {
          float a = F4E(R[1][i], e), b = F4E(R[2][i], e), c = F4E(R[3][i], e);
          float xx = F4E(R[0][i], e);
          float s = fabsf(a) + fabsf(b) + fabsf(c);
          float inv = (s >= 1.f) ? __builtin_amdgcn_rcpf(s) : 1.f;
          float cOk = (16 * k + 4 * cq + e > 0) ? 1.f : 0.f;  // global col 0
          float ga = a * inv * cOk * uOk;
          float gb = b * inv * cOk;
          float gc = c * inv * cOk * dOk;
          nx[e] = (1.f - ga - gb - gc) * xx;
          na[e] = ga; nb[e] = gb; nc[e] = gc;
        }
        R[0][i] = make_float4(nx[0], nx[1], nx[2], nx[3]);
        R[1][i] = make_float4(na[0], na[1], na[2], na[3]);
        R[2][i] = make_float4(nb[0], nb[1], nb[2], nb[3]);
        R[3][i] = make_float4(nc[0], nc[1], nc[2], nc[3]);
      }
    };

    // transpose-write one 8-col half into a stage buffer (column-major)
    auto writeHalf = [&](int hf, float* dst) {
      if (myhalf == hf) {
        const int c0 = 4 * cq - 8 * hf;        // 0 or 4
#pragma unroll
        for (int A = 0; A < 4; ++A)
#pragma unroll
          for (int i = 0; i < 4; ++i) {
            const int row = 64 * wid + 16 * i + rq;
#pragma unroll
            for (int e = 0; e < 4; ++e)
              dst[A * ARR_F + (c0 + e) * STG + row] = F4E(R[A][i], e);
          }
      }
    };

    // prologue: block0 -> stages 0,1; issue block1
    issueBlk(0);
    normBlk(0);
    writeHalf(0, lds_f + 0 * STAGE_F);
    writeHalf(1, lds_f + 1 * STAGE_F);
    issueBlk(1);
    FENCE_BAR();

#pragma unroll 1
    for (int t = 0; t < NS; ++t) {
      if (t + 2 < NS) {
        float* dst = lds_f + ((t + 2) % 3) * STAGE_F;
        if ((t & 1) == 0) {
          normBlk((t + 2) >> 1);        // compiler: counted vmcnt on R
          writeHalf(0, dst);            // stage t+2 (even: cols 0-7)
        } else {
          writeHalf(1, dst);            // stage t+2 (odd: cols 8-15)
          if (t <= 27) issueBlk((t + 3) >> 1);   // next block, 1 iter ahead
        }
      }
      FENCE_BAR();
    }
  } else {
    // ===================== CONSUMER (serial scan) =====================
    __builtin_amdgcn_s_setprio(1);
    float h[4] = {0.f, 0.f, 0.f, 0.f};
    const int cb = 4 * (l & 3);
    const int rr = l >> 2;
    float* tile = lds_f + TILE_OFF;

    FENCE_BAR();   // matches producer prologue barrier

#pragma unroll 1
    for (int t = 0; t < NS; ++t) {
      const float* src = lds_f + (t % 3) * STAGE_F;
      float* tl = tile + (t & 1) * (8 * STG);
#pragma unroll
      for (int c = 0; c < 8; ++c) {
        float4 d4 = *(const float4*)(src + 0 * ARR_F + c * STG + 4 * l);
        float4 a4 = *(const float4*)(src + 1 * ARR_F + c * STG + 4 * l);
        float4 b4 = *(const float4*)(src + 2 * ARR_F + c * STG + 4 * l);
        float4 c4 = *(const float4*)(src + 3 * ARR_F + c * STG + 4 * l);
        const float shU = __shfl_up(h[3], 1);    // h[4l-1]
        const float shD = __shfl_down(h[0], 1);  // h[4l+4]
        float hn[4];
#pragma unroll
        for (int r = 0; r < 4; ++r) {
          float up = (r == 0) ? shU : h[r - 1];
          float dn = (r == 3) ? shD : h[r + 1];
          hn[r] = fmaf(F4E(a4, r), up,
                  fmaf(F4E(b4, r), h[r],
                  fmaf(F4E(c4, r), dn, F4E(d4, r))));
        }
#pragma unroll
        for (int r = 0; r < 4; ++r) h[r] = hn[r];
        *(float4*)(tl + c * STG + 4 * l) = make_float4(hn[0], hn[1], hn[2], hn[3]);
      }
      if (t & 1) {
        // gather 16-col pair -> full 64B-line coalesced stores
        const int jc = 16 * (t >> 1);
#pragma unroll
        for (int kk = 0; kk < 16; ++kk) {
          const int row = 16 * kk + rr;
          float4 o;
          o.x = tile[(cb + 0) * STG + row];
          o.y = tile[(cb + 1) * STG + row];
          o.z = tile[(cb + 2) * STG + row];
          o.w = tile[(cb + 3) * STG + row];
          *(float4*)(op + (size_t)row * WD + jc + cb) = o;
        }
      }
      FENCE_BAR();
    }
  }
}

extern "C" void kernel_launch(void* const* d_in, const int* in_sizes, int n_in,
                              void* d_out, int out_size, void* d_ws, size_t ws_size,
                              hipStream_t stream) {
  const float* x  = (const float*)d_in[0];
  const float* g1 = (const float*)d_in[1];
  const float* g2 = (const float*)d_in[2];
  const float* g3 = (const float*)d_in[3];
  float* outp = (float*)d_out;
  const int planes = out_size / (HD * WD);   // B*C = 256
  spn_fwd<<<planes, 320, 0, stream>>>(x, g1, g2, g3, outp);
}

// Round 6
// 98.101 us; speedup vs baseline: 1.6900x; 1.0241x over previous
//
#include <hip/hip_runtime.h>

// SPN forward, round 6: producer/consumer specialization with a DEEP
// register pipeline. One block per (b,c) plane: 4 producer waves + 1
// consumer. Producers hold TWO 16-col blocks in regs (RA/RB); block k is
// issued 3 barrier-intervals before its use (norm+LDS write), hiding loaded
// HBM latency. 3-deep LDS stage ring, lgkm-only barriers (vmcnt stays in
// flight), uniform loop -> barrier matching by construction.
// Consumer: serial scan, lane l = rows 4l..4l+3 in regs, 2 shuffles/col,
// output transpose tile -> full-64B-line coalesced stores.

#define HD 256
#define WD 256
#define NS 32                   // 8-col stages
#define STG 260                 // padded column stride (floats)
#define ARR_F (8 * STG)
#define STAGE_F (4 * ARR_F)
#define TILE_OFF (3 * STAGE_F)

#define F4E(v, e) ((e) == 0 ? (v).x : (e) == 1 ? (v).y : (e) == 2 ? (v).z : (v).w)

#define FENCE_BAR()                                      \
  do {                                                   \
    asm volatile("s_waitcnt lgkmcnt(0)" ::: "memory");   \
    __builtin_amdgcn_s_barrier();                        \
    asm volatile("" ::: "memory");                       \
  } while (0)

__global__ __launch_bounds__(320, 1) void spn_fwd(
    const float* __restrict__ x, const float* __restrict__ G1,
    const float* __restrict__ G2, const float* __restrict__ G3,
    float* __restrict__ out)
{
  __shared__ float lds_f[3 * STAGE_F + 16 * STG];   // 116,480 B -> 1 block/CU

  const int tid = threadIdx.x;
  const int wid = tid >> 6;          // 0..3 producers, 4 consumer
  const int l   = tid & 63;
  const size_t pbase = (size_t)blockIdx.x * (HD * WD);
  const float* gp[4] = {x + pbase, G1 + pbase, G2 + pbase, G3 + pbase};
  float* op = out + pbase;

  if (wid < 4) {
    // ===================== PRODUCER (rows 64*wid .. +63) =====================
    const int rq = l >> 2;           // row within 16-row group
    const int cq = l & 3;            // col quad within 16-col block
    const int myhalf = cq >> 1;      // 0: block cols 0-7, 1: cols 8-15
    float4 RA[4][4], RB[4][4];       // two blocks in flight

    auto issueBlk = [&](float4 (&R)[4][4], int k) {
#pragma unroll
      for (int A = 0; A < 4; ++A)
#pragma unroll
        for (int i = 0; i < 4; ++i)
          R[A][i] = *(const float4*)(gp[A] +
              (size_t)(64 * wid + 16 * i + rq) * WD + 16 * k + 4 * cq);
    };

    auto normBlk = [&](float4 (&R)[4][4], int k) {
#pragma unroll
      for (int i = 0; i < 4; ++i) {
        const int row = 64 * wid + 16 * i + rq;
        const float uOk = (row > 0) ? 1.f : 0.f;
        const float dOk = (row < HD - 1) ? 1.f : 0.f;
        float nx[4], na[4], nb[4], nc[4];
#pragma unroll
        for (int e = 0; e < 4; ++e) {
          float a = F4E(R[1][i], e), b = F4E(R[2][i], e), c = F4E(R[3][i], e);
          float xx = F4E(R[0][i], e);
          float s = fabsf(a) + fabsf(b) + fabsf(c);
          float inv = (s >= 1.f) ? __builtin_amdgcn_rcpf(s) : 1.f;
          float cOk = (16 * k + 4 * cq + e > 0) ? 1.f : 0.f;  // global col 0
          float ga = a * inv * cOk * uOk;
          float gb = b * inv * cOk;
          float gc = c * inv * cOk * dOk;
          nx[e] = (1.f - ga - gb - gc) * xx;
          na[e] = ga; nb[e] = gb; nc[e] = gc;
        }
        R[0][i] = make_float4(nx[0], nx[1], nx[2], nx[3]);
        R[1][i] = make_float4(na[0], na[1], na[2], na[3]);
        R[2][i] = make_float4(nb[0], nb[1], nb[2], nb[3]);
        R[3][i] = make_float4(nc[0], nc[1], nc[2], nc[3]);
      }
    };

    auto writeHalf = [&](float4 (&R)[4][4], int hf, float* dst) {
      if (myhalf == hf) {
        const int c0 = 4 * cq - 8 * hf;        // 0 or 4
#pragma unroll
        for (int A = 0; A < 4; ++A)
#pragma unroll
          for (int i = 0; i < 4; ++i) {
            const int row = 64 * wid + 16 * i + rq;
#pragma unroll
            for (int e = 0; e < 4; ++e)
              dst[A * ARR_F + (c0 + e) * STG + row] = F4E(R[A][i], e);
          }
      }
    };

    // prologue: blocks 0,1 issued; block0 -> stages 0,1; block2 issued.
    issueBlk(RA, 0);
    issueBlk(RB, 1);
    normBlk(RA, 0);
    writeHalf(RA, 0, lds_f + 0 * STAGE_F);
    writeHalf(RA, 1, lds_f + 1 * STAGE_F);
    issueBlk(RA, 2);
    FENCE_BAR();

    // steady state: block k issued at t=2k-5, normed at t=2k-2 (gap 3).
#pragma unroll 1
    for (int tt = 0; tt < 8; ++tt) {
      const int t0 = 4 * tt;
      const int kb = t0 / 2;               // block index base
      // t = t0: norm RB (block kb+1), write half0 -> stage t0+2
      normBlk(RB, kb + 1);
      writeHalf(RB, 0, lds_f + ((t0 + 2) % 3) * STAGE_F);
      FENCE_BAR();
      // t = t0+1: write half1 -> stage t0+3; issue RB (block kb+3)
      writeHalf(RB, 1, lds_f + ((t0 + 3) % 3) * STAGE_F);
      if (kb + 3 <= 15) issueBlk(RB, kb + 3);
      FENCE_BAR();
      // t = t0+2: norm RA (block kb+2), write half0 -> stage t0+4
      if (kb + 2 <= 15) {
        normBlk(RA, kb + 2);
        writeHalf(RA, 0, lds_f + ((t0 + 4) % 3) * STAGE_F);
      }
      FENCE_BAR();
      // t = t0+3: write half1 -> stage t0+5; issue RA (block kb+4)
      if (kb + 2 <= 15) writeHalf(RA, 1, lds_f + ((t0 + 5) % 3) * STAGE_F);
      if (kb + 4 <= 15) issueBlk(RA, kb + 4);
      FENCE_BAR();
    }
  } else {
    // ===================== CONSUMER (serial scan) =====================
    __builtin_amdgcn_s_setprio(1);
    float h[4] = {0.f, 0.f, 0.f, 0.f};
    const int cb = 4 * (l & 3);
    const int rr = l >> 2;
    float* tile = lds_f + TILE_OFF;

    auto consume = [&](int t) {
      const float* src = lds_f + (t % 3) * STAGE_F;
      float* tl = tile + (t & 1) * (8 * STG);
#pragma unroll
      for (int c = 0; c < 8; ++c) {
        float4 d4 = *(const float4*)(src + 0 * ARR_F + c * STG + 4 * l);
        float4 a4 = *(const float4*)(src + 1 * ARR_F + c * STG + 4 * l);
        float4 b4 = *(const float4*)(src + 2 * ARR_F + c * STG + 4 * l);
        float4 c4 = *(const float4*)(src + 3 * ARR_F + c * STG + 4 * l);
        const float shU = __shfl_up(h[3], 1);    // h[4l-1]
        const float shD = __shfl_down(h[0], 1);  // h[4l+4]
        float hn[4];
#pragma unroll
        for (int r = 0; r < 4; ++r) {
          float up = (r == 0) ? shU : h[r - 1];
          float dn = (r == 3) ? shD : h[r + 1];
          hn[r] = fmaf(F4E(a4, r), up,
                  fmaf(F4E(b4, r), h[r],
                  fmaf(F4E(c4, r), dn, F4E(d4, r))));
        }
#pragma unroll
        for (int r = 0; r < 4; ++r) h[r] = hn[r];
        *(float4*)(tl + c * STG + 4 * l) = make_float4(hn[0], hn[1], hn[2], hn[3]);
      }
      if (t & 1) {
        const int jc = 16 * (t >> 1);
#pragma unroll
        for (int kk = 0; kk < 16; ++kk) {
          const int row = 16 * kk + rr;
          float4 o;
          o.x = tile[(cb + 0) * STG + row];
          o.y = tile[(cb + 1) * STG + row];
          o.z = tile[(cb + 2) * STG + row];
          o.w = tile[(cb + 3) * STG + row];
          *(float4*)(op + (size_t)row * WD + jc + cb) = o;
        }
      }
    };

    FENCE_BAR();   // matches producer prologue barrier

#pragma unroll 1
    for (int tt = 0; tt < 8; ++tt) {
      const int t0 = 4 * tt;
      consume(t0);     FENCE_BAR();
      consume(t0 + 1); FENCE_BAR();
      consume(t0 + 2); FENCE_BAR();
      consume(t0 + 3); FENCE_BAR();
    }
  }
}

extern "C" void kernel_launch(void* const* d_in, const int* in_sizes, int n_in,
                              void* d_out, int out_size, void* d_ws, size_t ws_size,
                              hipStream_t stream) {
  const float* x  = (const float*)d_in[0];
  const float* g1 = (const float*)d_in[1];
  const float* g2 = (const float*)d_in[2];
  const float* g3 = (const float*)d_in[3];
  float* outp = (float*)d_out;
  const int planes = out_size / (HD * WD);   // B*C = 256
  spn_fwd<<<planes, 320, 0, stream>>>(x, g1, g2, g3, outp);
}